// Round 5
// baseline (485.051 us; speedup 1.0000x reference)
//
#include <hip/hip_runtime.h>

#define NN 30000
#define NE 300000
#define HIDDEN 256

typedef __attribute__((ext_vector_type(8))) __bf16 bf16x8;
typedef __attribute__((ext_vector_type(4))) __bf16 bf16x4;
typedef __attribute__((ext_vector_type(4))) float float4v;

__device__ inline __bf16 f2bf(float f) {
  unsigned u = __builtin_bit_cast(unsigned, f);
  u += 0x7fffu + ((u >> 16) & 1u);
  unsigned short s = (unsigned short)(u >> 16);
  return __builtin_bit_cast(__bf16, s);
}
__device__ inline float bf2f(__bf16 b) {
  unsigned short s = __builtin_bit_cast(unsigned short, b);
  unsigned u = ((unsigned)s) << 16;
  return __builtin_bit_cast(float, u);
}
__device__ inline float gelu_tanh(float x) {
  float x3 = x * x * x;
  return 0.5f * x * (1.0f + tanhf(0.79788456080286536f * (x + 0.044715f * x3)));
}

// ---------------- prep kernels ----------------
__global__ void zero_int_kernel(int* __restrict__ p, int n) {
  int i = blockIdx.x * 256 + threadIdx.x;
  if (i < n) p[i] = 0;
}

__global__ void cvt_bf16_kernel(const float* __restrict__ x, __bf16* __restrict__ xb, int n8) {
  int t = blockIdx.x * 256 + threadIdx.x;
  if (t >= n8) return;
  const float* p = x + (size_t)t * 8;
  float4v f0 = *(const float4v*)(p);
  float4v f1 = *(const float4v*)(p + 4);
  bf16x8 b;
#pragma unroll
  for (int j = 0; j < 4; ++j) { b[j] = f2bf(f0[j]); b[j + 4] = f2bf(f1[j]); }
  *(bf16x8*)(xb + (size_t)t * 8) = b;
}

// Wqe[D][h*32+d] = sum_c Wq[D][h*32+c] * We[d][h*32+c]
__global__ void wqe_kernel(const float* __restrict__ Wq, const float* __restrict__ We,
                           float* __restrict__ Wqe) {
  int idx = blockIdx.x * 256 + threadIdx.x;
  if (idx >= 256 * 256) return;
  int D = idx >> 8, col = idx & 255;
  int h = col >> 5, d = col & 31;
  const float* wq = Wq + (size_t)D * 256 + h * 32;
  const float* we = We + (size_t)d * 256 + h * 32;
  float s = 0.f;
#pragma unroll
  for (int c = 0; c < 32; ++c) s += wq[c] * we[c];
  Wqe[idx] = s;
}

// ball[1280] = [bq | bk | bv | bqe | 0]
__global__ void ball_kernel(const float* __restrict__ bq, const float* __restrict__ bk,
                            const float* __restrict__ bv, const float* __restrict__ We,
                            float* __restrict__ ball) {
  int j = blockIdx.x * 256 + threadIdx.x;
  if (j >= 1280) return;
  float v = 0.f;
  if (j < 256) v = bq[j];
  else if (j < 512) v = bk[j - 256];
  else if (j < 768) v = bv[j - 512];
  else if (j < 1024) {
    int col = j - 768, h = col >> 5, d = col & 31;
    const float* bqh = bq + h * 32;
    const float* we = We + (size_t)d * 256 + h * 32;
    float s = 0.f;
#pragma unroll
    for (int c = 0; c < 32; ++c) s += bqh[c] * we[c];
    v = s;
  }
  ball[j] = v;
}

// WeT[ch][d] = We[d][ch]  (fp32, 256x32)
__global__ void wet_kernel(const float* __restrict__ We, float* __restrict__ WeT) {
  int idx = blockIdx.x * 256 + threadIdx.x;
  if (idx >= 256 * 32) return;
  int ch = idx >> 5, d = idx & 31;
  WeT[idx] = We[(size_t)d * 256 + ch];
}

// Wt[n][k] (bf16) = W[k][n]; 256x256 chunk
__global__ void transpose_w_kernel(const float* __restrict__ W, __bf16* __restrict__ Wt) {
  int idx = blockIdx.x * 256 + threadIdx.x;
  if (idx >= 256 * 256) return;
  int k = idx & 255, n = idx >> 8;
  Wt[idx] = f2bf(W[(size_t)k * 256 + n]);
}

// ---------------- CSR build ----------------
__global__ void count_deg_kernel(const int* __restrict__ dst, int* __restrict__ deg, int E) {
  int e = blockIdx.x * 256 + threadIdx.x;
  if (e < E) atomicAdd(&deg[dst[e]], 1);
}

__global__ __launch_bounds__(1024) void scan_kernel(const int* __restrict__ deg,
                                                    int* __restrict__ offs, int n) {
  __shared__ int part[1024];
  const int tid = threadIdx.x;
  const int per = (n + 1023) / 1024;
  const int base = tid * per;
  int s = 0;
  for (int j = 0; j < per; ++j) {
    int i = base + j;
    if (i < n) s += deg[i];
  }
  part[tid] = s;
  __syncthreads();
  for (int st = 1; st < 1024; st <<= 1) {
    int t = (tid >= st) ? part[tid - st] : 0;
    __syncthreads();
    part[tid] += t;
    __syncthreads();
  }
  int run = (tid > 0) ? part[tid - 1] : 0;
  for (int j = 0; j < per; ++j) {
    int i = base + j;
    if (i < n) { offs[i] = run; run += deg[i]; }
  }
  if (tid == 1023) offs[n] = part[1023];
}

__global__ void scatter_kernel(const int* __restrict__ srcIn, const int* __restrict__ dstIn,
                               const int* __restrict__ offs, int* __restrict__ cursor,
                               int* __restrict__ srcs, int* __restrict__ eids, int E) {
  int e = blockIdx.x * 256 + threadIdx.x;
  if (e >= E) return;
  int d = dstIn[e];
  int p = atomicAdd(&cursor[d], 1);
  int o = offs[d] + p;
  srcs[o] = srcIn[e];
  eids[o] = e;
}

// eaC[o][0..32) = bf16(ea[eids[o]][0..32))
__global__ void gather_ea_kernel(const float* __restrict__ ea, const int* __restrict__ eids,
                                 __bf16* __restrict__ eaC, int E) {
  int t = blockIdx.x * 256 + threadIdx.x;
  if (t >= E * 4) return;
  int o = t >> 2, part = t & 3;
  int e = eids[o];
  const float* src = ea + (size_t)e * 32 + part * 8;
  float4v f0 = *(const float4v*)(src);
  float4v f1 = *(const float4v*)(src + 4);
  bf16x8 b;
#pragma unroll
  for (int j = 0; j < 4; ++j) { b[j] = f2bf(f0[j]); b[j + 4] = f2bf(f1[j]); }
  *(bf16x8*)(eaC + (size_t)o * 32 + part * 8) = b;
}

// ---------------- MFMA GEMM v3 ----------------
// A bf16 [M][256], Wt bf16 [N][256] (N = GX*128). Block = 128x128, per-wave
// 32x128. B^T tile staged once in LDS (stride 264). XCD swizzle: bid%8 = row
// stripe. MODE 0: EPI 1=fp32, 2=+bias gelu bf16, 3=+bias gelu +resid fp32.
// MODE 1 (fused, GX=10): cols 0-1023 -> QG/KV interleaved planes (bf16,
// per-lane [q4|g4] / [k4|v4] groups), cols 1024-1279 -> skip fp32 to Yf.
template <int GX, int EPI, int MODE>
__global__ __launch_bounds__(256) void gemm_k3(
    const __bf16* __restrict__ A, const __bf16* __restrict__ Wt,
    const float* __restrict__ bias,
    float* __restrict__ Yf, __bf16* __restrict__ Ybf, __bf16* __restrict__ KVp,
    const float* __restrict__ resid, int M, int gyTiles) {
  __shared__ __bf16 Bs[128 * 264];
  const int bid = blockIdx.x;
  const int stripe = bid / (8 * GX);
  const int rem = bid % (8 * GX);
  const int y8 = rem % 8;
  const int xt = rem / 8;
  const int y = stripe * 8 + y8;
  if (y >= gyTiles) return;
  const int n0 = xt * 128;

  {
    const int t = threadIdx.x;
#pragma unroll
    for (int i = 0; i < 16; ++i) {
      int g = i * 256 + t;
      int row = g >> 5;
      int c16 = g & 31;
      bf16x8 v = *(const bf16x8*)(Wt + (size_t)(n0 + row) * 256 + c16 * 8);
      *(bf16x8*)(Bs + row * 264 + c16 * 8) = v;
    }
  }
  __syncthreads();

  const int lane = threadIdx.x & 63;
  const int w = threadIdx.x >> 6;
  const int r = lane & 15;
  const int q = lane >> 4;
  const int mw = y * 128 + w * 32;
  int ar0 = mw + r;      if (ar0 >= M) ar0 = M - 1;
  int ar1 = mw + 16 + r; if (ar1 >= M) ar1 = M - 1;
  const int kq = q * 8;

  float4v acc[2][8];
#pragma unroll
  for (int i = 0; i < 2; ++i)
#pragma unroll
    for (int t = 0; t < 8; ++t) acc[i][t] = (float4v){0.f, 0.f, 0.f, 0.f};

#pragma unroll
  for (int kk = 0; kk < 256; kk += 32) {
    const int ka = kk + kq;
    bf16x8 a0 = *(const bf16x8*)(A + (size_t)ar0 * 256 + ka);
    bf16x8 a1 = *(const bf16x8*)(A + (size_t)ar1 * 256 + ka);
    bf16x8 b[8];
#pragma unroll
    for (int t = 0; t < 8; ++t)
      b[t] = *(const bf16x8*)(Bs + (t * 16 + r) * 264 + ka);
#pragma unroll
    for (int t = 0; t < 8; ++t) {
      acc[0][t] = __builtin_amdgcn_mfma_f32_16x16x32_bf16(a0, b[t], acc[0][t], 0, 0, 0);
      acc[1][t] = __builtin_amdgcn_mfma_f32_16x16x32_bf16(a1, b[t], acc[1][t], 0, 0, 0);
    }
  }

  constexpr int NSTR = GX * 128;
#pragma unroll
  for (int t = 0; t < 8; ++t) {
    const int col = n0 + t * 16 + r;
    const float bb = bias ? bias[col] : 0.0f;
#pragma unroll
    for (int i2 = 0; i2 < 2; ++i2) {
#pragma unroll
      for (int ii = 0; ii < 4; ++ii) {
        const int row = mw + i2 * 16 + q * 4 + ii;
        if (row < M) {
          float v = acc[i2][t][ii] + bb;
          if constexpr (EPI == 2 || EPI == 3) v = gelu_tanh(v);
          if constexpr (MODE == 1) {
            const int p = col >> 8;
            const int c = col & 255;
            if (p == 4) {
              Yf[(size_t)row * 256 + c] = v;
            } else {
              const int g = ((c >> 2) << 3) | (c & 3);
              const __bf16 bv16 = f2bf(v);
              if (p == 0)      Ybf[(size_t)row * 512 + g] = bv16;
              else if (p == 3) Ybf[(size_t)row * 512 + g + 4] = bv16;
              else if (p == 1) KVp[(size_t)row * 512 + g] = bv16;
              else             KVp[(size_t)row * 512 + g + 4] = bv16;
            }
          } else {
            const size_t off = (size_t)row * NSTR + col;
            if constexpr (EPI == 3) v += resid[off];
            if constexpr (EPI == 1 || EPI == 3) Yf[off] = v;
            else Ybf[off] = f2bf(v);
          }
        }
      }
    }
  }
}

// ---------------- attention: one block (4 waves) per dst node ----------------
// Plain exp (no max-sub: |logit| < ~10, safe in fp32). Lane owns channels
// c0=lane*4 (head hg=lane>>3) and edge-dims (lane&7)*4 of its head.
// QG/KV are per-lane interleaved: [n][lane][q0..3 g0..3] / [k0..3 v0..3].
__global__ __launch_bounds__(256) void attn_kernel(
    const __bf16* __restrict__ QG, const __bf16* __restrict__ KV,
    const __bf16* __restrict__ eaC,
    const int* __restrict__ offs, const int* __restrict__ srcs,
    float* __restrict__ OUT, __bf16* __restrict__ AE) {
  __shared__ float sdn[4][64];
  __shared__ float sav[4][64][4], sae[4][64][4];
  const int lane = threadIdx.x & 63;
  const int w = threadIdx.x >> 6;
  const int n = blockIdx.x;
  const int c0 = lane * 4;
  const int sub = lane & 7;

  const bf16x8 qg = *(const bf16x8*)(QG + (size_t)n * 512 + lane * 8);
  const float q0 = bf2f(qg[0]), q1 = bf2f(qg[1]), q2 = bf2f(qg[2]), q3 = bf2f(qg[3]);
  const float g0 = bf2f(qg[4]), g1 = bf2f(qg[5]), g2 = bf2f(qg[6]), g3 = bf2f(qg[7]);

  float denom = 0.f;
  float4v accv = {0.f, 0.f, 0.f, 0.f};
  float4v acce = {0.f, 0.f, 0.f, 0.f};
  const int beg = offs[n], end = offs[n + 1];
  for (int i = beg + w; i < end; i += 4) {
    const int sn = srcs[i];
    const bf16x8 kv = *(const bf16x8*)(KV + (size_t)sn * 512 + lane * 8);
    const bf16x4 e4 = *(const bf16x4*)(eaC + (size_t)i * 32 + sub * 4);
    const float e0 = bf2f(e4[0]), e1 = bf2f(e4[1]), e2 = bf2f(e4[2]), e3 = bf2f(e4[3]);
    float part = q0 * bf2f(kv[0]) + q1 * bf2f(kv[1]) + q2 * bf2f(kv[2]) + q3 * bf2f(kv[3])
               + g0 * e0 + g1 * e1 + g2 * e2 + g3 * e3;
    part += __shfl_xor(part, 1);
    part += __shfl_xor(part, 2);
    part += __shfl_xor(part, 4);
    const float wgt = __expf(part * 0.17677669529663687f);  // 1/sqrt(32)
    denom += wgt;
    accv[0] += wgt * bf2f(kv[4]);
    accv[1] += wgt * bf2f(kv[5]);
    accv[2] += wgt * bf2f(kv[6]);
    accv[3] += wgt * bf2f(kv[7]);
    acce[0] += wgt * e0;
    acce[1] += wgt * e1;
    acce[2] += wgt * e2;
    acce[3] += wgt * e3;
  }
  sdn[w][lane] = denom;
#pragma unroll
  for (int j = 0; j < 4; ++j) { sav[w][lane][j] = accv[j]; sae[w][lane][j] = acce[j]; }
  __syncthreads();
  if (w == 0) {
    float D = 0.f;
    float4v av = {0.f, 0.f, 0.f, 0.f};
    float4v ae = {0.f, 0.f, 0.f, 0.f};
#pragma unroll
    for (int ww = 0; ww < 4; ++ww) {
      D += sdn[ww][lane];
#pragma unroll
      for (int j = 0; j < 4; ++j) { av[j] += sav[ww][lane][j]; ae[j] += sae[ww][lane][j]; }
    }
    const float inv = 1.0f / (D + 1e-16f);
    float4v o = *(const float4v*)(OUT + (size_t)n * 256 + c0);
#pragma unroll
    for (int j = 0; j < 4; ++j) o[j] += av[j] * inv;
    *(float4v*)(OUT + (size_t)n * 256 + c0) = o;
    bf16x4 aeb;
    aeb[0] = f2bf(ae[0] * inv); aeb[1] = f2bf(ae[1] * inv);
    aeb[2] = f2bf(ae[2] * inv); aeb[3] = f2bf(ae[3] * inv);
    *(bf16x4*)(AE + (size_t)n * 256 + c0) = aeb;
  }
}

// ---------------- post: OUT += AE@We (per-head); OUTh = bf16(OUT) ----------------
__global__ __launch_bounds__(256) void post_kernel(
    const __bf16* __restrict__ AE, const float* __restrict__ WeT,
    float* __restrict__ OUT, __bf16* __restrict__ OUTh) {
  const int lane = threadIdx.x & 63;
  const int wave = threadIdx.x >> 6;
  const int c0 = lane * 4;
  const int hg = lane >> 3;

  float4v w4[4][8];
#pragma unroll
  for (int j = 0; j < 4; ++j)
#pragma unroll
    for (int s = 0; s < 8; ++s)
      w4[j][s] = *(const float4v*)(WeT + (size_t)(c0 + j) * 32 + s * 4);

  const int nbase = blockIdx.x * 64;
  for (int it = 0; it < 16; ++it) {
    const int n = nbase + it * 4 + wave;
    if (n >= NN) return;
    const __bf16* aerow = AE + (size_t)n * HIDDEN + hg * 32;
    float aef[32];
#pragma unroll
    for (int t = 0; t < 4; ++t) {
      bf16x8 a8 = *(const bf16x8*)(aerow + t * 8);
#pragma unroll
      for (int j = 0; j < 8; ++j) aef[t * 8 + j] = bf2f(a8[j]);
    }
    float4v o = *(const float4v*)(OUT + (size_t)n * HIDDEN + c0);
#pragma unroll
    for (int j = 0; j < 4; ++j) {
      float s = 0.f;
#pragma unroll
      for (int g = 0; g < 8; ++g) {
        s += aef[g * 4 + 0] * w4[j][g][0] + aef[g * 4 + 1] * w4[j][g][1]
           + aef[g * 4 + 2] * w4[j][g][2] + aef[g * 4 + 3] * w4[j][g][3];
      }
      o[j] += s;
    }
    *(float4v*)(OUT + (size_t)n * HIDDEN + c0) = o;
    bf16x4 ob;
    ob[0] = f2bf(o[0]); ob[1] = f2bf(o[1]); ob[2] = f2bf(o[2]); ob[3] = f2bf(o[3]);
    *(bf16x4*)(OUTh + (size_t)n * HIDDEN + c0) = ob;
  }
}

extern "C" void kernel_launch(void* const* d_in, const int* in_sizes, int n_in,
                              void* d_out, int out_size, void* d_ws, size_t ws_size,
                              hipStream_t stream) {
  (void)in_sizes; (void)n_in; (void)out_size; (void)ws_size;
  const float* x   = (const float*)d_in[0];
  const int*   ei  = (const int*)d_in[1];
  const float* ea  = (const float*)d_in[2];
  const float* Wq  = (const float*)d_in[3];
  const float* bq  = (const float*)d_in[4];
  const float* Wk  = (const float*)d_in[5];
  const float* bk  = (const float*)d_in[6];
  const float* Wv  = (const float*)d_in[7];
  const float* bv  = (const float*)d_in[8];
  const float* We  = (const float*)d_in[9];
  const float* Wsk = (const float*)d_in[10];
  const float* W1  = (const float*)d_in[11];
  const float* b1  = (const float*)d_in[12];
  const float* W2  = (const float*)d_in[13];
  const float* b2  = (const float*)d_in[14];
  float* out = (float*)d_out;

  char* ws = (char*)d_ws;
  size_t off = 0;
  auto alloc = [&](size_t bytes) -> char* {
    off = (off + 255) & ~(size_t)255;
    char* p = ws + off;
    off += bytes;
    return p;
  };
  __bf16* QG   = (__bf16*)alloc((size_t)NN * 512 * 2);
  __bf16* KV   = (__bf16*)alloc((size_t)NN * 512 * 2);
  __bf16* xb   = (__bf16*)alloc((size_t)NN * 256 * 2);
  __bf16* AE   = (__bf16*)alloc((size_t)NN * 256 * 2);      // reused as H1
  __bf16* OUTh = (__bf16*)alloc((size_t)NN * 256 * 2);
  __bf16* eaC  = (__bf16*)alloc((size_t)NE * 32 * 2);
  __bf16* WTall = (__bf16*)alloc((size_t)1280 * 256 * 2);
  __bf16* WT1  = (__bf16*)alloc(256 * 256 * 2);
  __bf16* WT2  = (__bf16*)alloc(256 * 256 * 2);
  float*  Wqe  = (float*)alloc(256 * 256 * 4);
  float*  ball = (float*)alloc(1280 * 4);
  float*  WeT  = (float*)alloc(256 * 32 * 4);
  int* deg    = (int*)alloc((size_t)2 * NN * 4);
  int* cursor = deg + NN;
  int* offs   = (int*)alloc((size_t)(NN + 1) * 4);
  int* srcs   = (int*)alloc((size_t)NE * 4);
  int* eids   = (int*)alloc((size_t)NE * 4);
  __bf16* H1 = AE;

  const int* srcIn = ei;       // edge_index[0]
  const int* dstIn = ei + NE;  // edge_index[1]

  // ---- prep ----
  cvt_bf16_kernel<<<(NN * 256 / 8 + 255) / 256, 256, 0, stream>>>(x, xb, NN * 256 / 8);
  wqe_kernel<<<256, 256, 0, stream>>>(Wq, We, Wqe);
  ball_kernel<<<5, 256, 0, stream>>>(bq, bk, bv, We, ball);
  wet_kernel<<<32, 256, 0, stream>>>(We, WeT);
  transpose_w_kernel<<<256, 256, 0, stream>>>(Wq, WTall);
  transpose_w_kernel<<<256, 256, 0, stream>>>(Wk, WTall + 256 * 256);
  transpose_w_kernel<<<256, 256, 0, stream>>>(Wv, WTall + 2 * 256 * 256);
  transpose_w_kernel<<<256, 256, 0, stream>>>(Wqe, WTall + 3 * 256 * 256);
  transpose_w_kernel<<<256, 256, 0, stream>>>(Wsk, WTall + 4 * 256 * 256);
  transpose_w_kernel<<<256, 256, 0, stream>>>(W1, WT1);
  transpose_w_kernel<<<256, 256, 0, stream>>>(W2, WT2);

  // ---- CSR build + CSR-ordered edge attrs ----
  zero_int_kernel<<<(2 * NN + 255) / 256, 256, 0, stream>>>(deg, 2 * NN);
  count_deg_kernel<<<(NE + 255) / 256, 256, 0, stream>>>(dstIn, deg, NE);
  scan_kernel<<<1, 1024, 0, stream>>>(deg, offs, NN);
  scatter_kernel<<<(NE + 255) / 256, 256, 0, stream>>>(srcIn, dstIn, offs, cursor, srcs, eids, NE);
  gather_ea_kernel<<<(NE * 4 + 255) / 256, 256, 0, stream>>>(ea, eids, eaC, NE);

  const int gy = (NN + 127) / 128;          // 235
  const int stripes = (gy + 7) / 8;         // 30
  // ---- fused node GEMM: Q|K|V|QE -> QG/KV interleaved planes, skip -> out ----
  gemm_k3<10, 0, 1><<<stripes * 80, 256, 0, stream>>>(
      xb, WTall, ball, out, QG, KV, nullptr, NN, gy);

  // ---- attention (RMW out, write AE) ----
  attn_kernel<<<NN, 256, 0, stream>>>(QG, KV, eaC, offs, srcs, out, AE);

  // ---- post: out += AE @ We (per-head), OUTh = bf16(out) ----
  post_kernel<<<(NN + 63) / 64, 256, 0, stream>>>(AE, WeT, out, OUTh);

  // ---- MLP ----
  gemm_k3<2, 2, 0><<<stripes * 16, 256, 0, stream>>>(
      OUTh, WT1, b1, nullptr, H1, nullptr, nullptr, NN, gy);
  gemm_k3<2, 3, 0><<<stripes * 16, 256, 0, stream>>>(
      H1, WT2, b2, out, nullptr, nullptr, out, NN, gy);
}

// Round 6
// 403.609 us; speedup vs baseline: 1.2018x; 1.2018x over previous
//
#include <hip/hip_runtime.h>

#define NN 30000
#define NE 300000
#define HIDDEN 256

typedef __attribute__((ext_vector_type(8))) __bf16 bf16x8;
typedef __attribute__((ext_vector_type(4))) __bf16 bf16x4;
typedef __attribute__((ext_vector_type(4))) float float4v;

__device__ inline __bf16 f2bf(float f) {
  unsigned u = __builtin_bit_cast(unsigned, f);
  u += 0x7fffu + ((u >> 16) & 1u);
  unsigned short s = (unsigned short)(u >> 16);
  return __builtin_bit_cast(__bf16, s);
}
__device__ inline float bf2f(__bf16 b) {
  unsigned short s = __builtin_bit_cast(unsigned short, b);
  unsigned u = ((unsigned)s) << 16;
  return __builtin_bit_cast(float, u);
}
__device__ inline float gelu_tanh(float x) {
  float x3 = x * x * x;
  return 0.5f * x * (1.0f + tanhf(0.79788456080286536f * (x + 0.044715f * x3)));
}

// ---------------- fused prep: 7 weight transposes + ball + WeT + x->bf16 ----------------
// blocks 0..1791: transpose region b>>8 (0=Wq,1=Wk,2=Wv,3=Wqe(fused),4=Wsk,5=W1,6=W2)
// blocks 1792..1796: ball[1280]; blocks 1797..1828: WeT; blocks 1829+: x cvt
__global__ __launch_bounds__(256) void prep_kernel(
    const float* __restrict__ Wq, const float* __restrict__ Wk, const float* __restrict__ Wv,
    const float* __restrict__ Wsk, const float* __restrict__ W1, const float* __restrict__ W2,
    const float* __restrict__ We, const float* __restrict__ bq, const float* __restrict__ bk,
    const float* __restrict__ bv, const float* __restrict__ x,
    __bf16* __restrict__ WTall, __bf16* __restrict__ WT1, __bf16* __restrict__ WT2,
    float* __restrict__ ball, float* __restrict__ WeT, __bf16* __restrict__ xb) {
  const int b = blockIdx.x;
  const int tid = threadIdx.x;
  if (b < 1792) {
    const int region = b >> 8;
    const int idx = ((b & 255) << 8) | tid;  // [n(8b)|k(8b)] -> Wt[n][k]
    const int k = idx & 255, n = idx >> 8;
    float v;
    if (region == 3) {  // Wqe[k][n] on the fly: n = h*32+d
      const int h = n >> 5, d = n & 31;
      const float* wq = Wq + (size_t)k * 256 + h * 32;
      const float* we = We + (size_t)d * 256 + h * 32;
      float s = 0.f;
#pragma unroll
      for (int c = 0; c < 32; ++c) s += wq[c] * we[c];
      v = s;
    } else {
      const float* W = (region == 0) ? Wq : (region == 1) ? Wk : (region == 2) ? Wv
                     : (region == 4) ? Wsk : (region == 5) ? W1 : W2;
      v = W[(size_t)k * 256 + n];
    }
    const __bf16 bv16 = f2bf(v);
    if (region < 5) WTall[(size_t)region * 65536 + idx] = bv16;
    else if (region == 5) WT1[idx] = bv16;
    else WT2[idx] = bv16;
  } else if (b < 1797) {
    const int j = (b - 1792) * 256 + tid;
    if (j < 1280) {
      float v = 0.f;
      if (j < 256) v = bq[j];
      else if (j < 512) v = bk[j - 256];
      else if (j < 768) v = bv[j - 512];
      else if (j < 1024) {
        const int col = j - 768, h = col >> 5, d = col & 31;
        const float* bqh = bq + h * 32;
        const float* we = We + (size_t)d * 256 + h * 32;
        float s = 0.f;
#pragma unroll
        for (int c = 0; c < 32; ++c) s += bqh[c] * we[c];
        v = s;
      }
      ball[j] = v;
    }
  } else if (b < 1829) {
    const int idx = (b - 1797) * 256 + tid;  // < 8192
    const int ch = idx >> 5, d = idx & 31;
    WeT[idx] = We[(size_t)d * 256 + ch];
  } else {
    const int t = (b - 1829) * 256 + tid;
    if (t < NN * 256 / 8) {
      const float* p = x + (size_t)t * 8;
      float4v f0 = *(const float4v*)(p);
      float4v f1 = *(const float4v*)(p + 4);
      bf16x8 o;
#pragma unroll
      for (int j = 0; j < 4; ++j) { o[j] = f2bf(f0[j]); o[j + 4] = f2bf(f1[j]); }
      *(bf16x8*)(xb + (size_t)t * 8) = o;
    }
  }
}

// ---------------- CSR build ----------------
__global__ void zero_int_kernel(int* __restrict__ p, int n) {
  int i = blockIdx.x * 256 + threadIdx.x;
  if (i < n) p[i] = 0;
}

__global__ void count_deg_kernel(const int* __restrict__ dst, int* __restrict__ deg, int E) {
  int e = blockIdx.x * 256 + threadIdx.x;
  if (e < E) atomicAdd(&deg[dst[e]], 1);
}

__global__ __launch_bounds__(1024) void scan_kernel(const int* __restrict__ deg,
                                                    int* __restrict__ offs, int n) {
  __shared__ int part[1024];
  const int tid = threadIdx.x;
  const int per = (n + 1023) / 1024;
  const int base = tid * per;
  int s = 0;
  for (int j = 0; j < per; ++j) {
    int i = base + j;
    if (i < n) s += deg[i];
  }
  part[tid] = s;
  __syncthreads();
  for (int st = 1; st < 1024; st <<= 1) {
    int t = (tid >= st) ? part[tid - st] : 0;
    __syncthreads();
    part[tid] += t;
    __syncthreads();
  }
  int run = (tid > 0) ? part[tid - 1] : 0;
  for (int j = 0; j < per; ++j) {
    int i = base + j;
    if (i < n) { offs[i] = run; run += deg[i]; }
  }
  if (tid == 1023) offs[n] = part[1023];
}

__global__ void scatter_kernel(const int* __restrict__ srcIn, const int* __restrict__ dstIn,
                               const int* __restrict__ offs, int* __restrict__ cursor,
                               int* __restrict__ srcs, int* __restrict__ eids, int E) {
  int e = blockIdx.x * 256 + threadIdx.x;
  if (e >= E) return;
  int d = dstIn[e];
  int p = atomicAdd(&cursor[d], 1);
  int o = offs[d] + p;
  srcs[o] = srcIn[e];
  eids[o] = e;
}

// eaC[o][0..32) = bf16(ea[eids[o]][0..32))
__global__ void gather_ea_kernel(const float* __restrict__ ea, const int* __restrict__ eids,
                                 __bf16* __restrict__ eaC, int E) {
  int t = blockIdx.x * 256 + threadIdx.x;
  if (t >= E * 4) return;
  int o = t >> 2, part = t & 3;
  int e = eids[o];
  const float* src = ea + (size_t)e * 32 + part * 8;
  float4v f0 = *(const float4v*)(src);
  float4v f1 = *(const float4v*)(src + 4);
  bf16x8 b;
#pragma unroll
  for (int j = 0; j < 4; ++j) { b[j] = f2bf(f0[j]); b[j + 4] = f2bf(f1[j]); }
  *(bf16x8*)(eaC + (size_t)o * 32 + part * 8) = b;
}

// ---------------- MFMA GEMM v4: LDS B-tile + LDS-staged coalesced epilogue ----
// A bf16 [M][256], Wt bf16 [N][256] (N = GX*128). Block = 128x128, per-wave
// 32x128. After K-loop the B-tile LDS is reused as per-wave fp32 C-stage
// (32 x stride-132), then read back float4 and stored vectorized.
// MODE 0: EPI 1=fp32, 2=+bias gelu bf16, 3=+bias gelu +resid fp32.
// MODE 1 (GX=10): planes 0..3 -> QG/KV interleaved bf16, plane 4 -> skip fp32.
template <int GX, int EPI, int MODE>
__global__ __launch_bounds__(256) void gemm_k4(
    const __bf16* __restrict__ A, const __bf16* __restrict__ Wt,
    const float* __restrict__ bias,
    float* __restrict__ Yf, __bf16* __restrict__ Ybf,
    __bf16* __restrict__ QGp, __bf16* __restrict__ KVp,
    const float* __restrict__ resid, int M, int gyTiles) {
  __shared__ char smem[128 * 264 * 2];  // 67584 B: B-tile, then C-stage (4x16896B)
  __bf16* Bs = (__bf16*)smem;
  const int bid = blockIdx.x;
  const int stripe = bid / (8 * GX);
  const int rem = bid % (8 * GX);
  const int y8 = rem % 8;   // XCD id: col-blocks of one row-stripe share an XCD
  const int xt = rem / 8;
  const int y = stripe * 8 + y8;
  if (y >= gyTiles) return;
  const int n0 = xt * 128;

  {
    const int t = threadIdx.x;
#pragma unroll
    for (int i = 0; i < 16; ++i) {
      int g = i * 256 + t;
      int row = g >> 5;
      int c16 = g & 31;
      bf16x8 v = *(const bf16x8*)(Wt + (size_t)(n0 + row) * 256 + c16 * 8);
      *(bf16x8*)(Bs + row * 264 + c16 * 8) = v;
    }
  }
  __syncthreads();

  const int lane = threadIdx.x & 63;
  const int w = threadIdx.x >> 6;
  const int r = lane & 15;
  const int q = lane >> 4;
  const int mw = y * 128 + w * 32;
  int ar0 = mw + r;      if (ar0 >= M) ar0 = M - 1;
  int ar1 = mw + 16 + r; if (ar1 >= M) ar1 = M - 1;
  const int kq = q * 8;

  float4v acc[2][8];
#pragma unroll
  for (int i = 0; i < 2; ++i)
#pragma unroll
    for (int t = 0; t < 8; ++t) acc[i][t] = (float4v){0.f, 0.f, 0.f, 0.f};

#pragma unroll
  for (int kk = 0; kk < 256; kk += 32) {
    const int ka = kk + kq;
    bf16x8 a0 = *(const bf16x8*)(A + (size_t)ar0 * 256 + ka);
    bf16x8 a1 = *(const bf16x8*)(A + (size_t)ar1 * 256 + ka);
    bf16x8 b[8];
#pragma unroll
    for (int t = 0; t < 8; ++t)
      b[t] = *(const bf16x8*)(Bs + (t * 16 + r) * 264 + ka);
#pragma unroll
    for (int t = 0; t < 8; ++t) {
      acc[0][t] = __builtin_amdgcn_mfma_f32_16x16x32_bf16(a0, b[t], acc[0][t], 0, 0, 0);
      acc[1][t] = __builtin_amdgcn_mfma_f32_16x16x32_bf16(a1, b[t], acc[1][t], 0, 0, 0);
    }
  }
  __syncthreads();  // B-tile dead; reuse LDS as C-stage

  // stage C (fp32, stride 132) with bias/gelu applied
  float* cs = (float*)smem + w * 4224;  // 32*132 floats per wave
#pragma unroll
  for (int t = 0; t < 8; ++t) {
    const int col = n0 + t * 16 + r;
    const float bb = bias ? bias[col] : 0.0f;
#pragma unroll
    for (int i2 = 0; i2 < 2; ++i2)
#pragma unroll
      for (int ii = 0; ii < 4; ++ii) {
        float v = acc[i2][t][ii] + bb;
        if constexpr (EPI == 2 || EPI == 3) v = gelu_tanh(v);
        cs[(i2 * 16 + q * 4 + ii) * 132 + t * 16 + r] = v;
      }
  }

  // coalesced read-back + vector stores (per-wave region; same-wave LDS order ok)
  constexpr int NSTR = GX * 128;
  const int p = n0 >> 8;
  const int cbase = n0 & 255;
  __bf16* dstI = (p == 0 || p == 3) ? QGp : KVp;
  const int moff = (p >= 2) ? 4 : 0;  // planes 2(V),3(G) are second member
#pragma unroll
  for (int i = 0; i < 16; ++i) {
    const int rl = i * 2 + (lane >> 5);
    const int row = mw + rl;
    const int c4 = (lane & 31) * 4;
    float4v v = *(const float4v*)(cs + rl * 132 + c4);
    if (row < M) {
      if constexpr (MODE == 1) {
        if (p == 4) {
          *(float4v*)(Yf + (size_t)row * 256 + cbase + c4) = v;
        } else {
          bf16x4 b4;
          b4[0] = f2bf(v[0]); b4[1] = f2bf(v[1]); b4[2] = f2bf(v[2]); b4[3] = f2bf(v[3]);
          const int c = cbase + c4;
          *(bf16x4*)(dstI + (size_t)row * 512 + 2 * c + moff) = b4;
        }
      } else if constexpr (EPI == 1) {
        *(float4v*)(Yf + (size_t)row * NSTR + n0 + c4) = v;
      } else if constexpr (EPI == 3) {
        float4v rr = *(const float4v*)(resid + (size_t)row * NSTR + n0 + c4);
        v[0] += rr[0]; v[1] += rr[1]; v[2] += rr[2]; v[3] += rr[3];
        *(float4v*)(Yf + (size_t)row * NSTR + n0 + c4) = v;
      } else {  // bf16 out
        bf16x4 b4;
        b4[0] = f2bf(v[0]); b4[1] = f2bf(v[1]); b4[2] = f2bf(v[2]); b4[3] = f2bf(v[3]);
        *(bf16x4*)(Ybf + (size_t)row * NSTR + n0 + c4) = b4;
      }
    }
  }
}

// ---------------- attention: one block (4 waves) per dst node ----------------
// Plain exp (no max-sub: |logit| small, fp32-safe). Lane owns channels
// c0=lane*4 (head hg=lane>>3) and edge-dims (lane&7)*4 of its head.
// QG/KV per-lane interleaved: [n][lane][q0..3 g0..3] / [k0..3 v0..3].
__global__ __launch_bounds__(256) void attn_kernel(
    const __bf16* __restrict__ QG, const __bf16* __restrict__ KV,
    const __bf16* __restrict__ eaC,
    const int* __restrict__ offs, const int* __restrict__ srcs,
    float* __restrict__ OUT, __bf16* __restrict__ AE) {
  __shared__ float sdn[4][64];
  __shared__ float sav[4][64][4], sae[4][64][4];
  const int lane = threadIdx.x & 63;
  const int w = threadIdx.x >> 6;
  const int n = blockIdx.x;
  const int c0 = lane * 4;
  const int sub = lane & 7;

  const bf16x8 qg = *(const bf16x8*)(QG + (size_t)n * 512 + lane * 8);
  const float q0 = bf2f(qg[0]), q1 = bf2f(qg[1]), q2 = bf2f(qg[2]), q3 = bf2f(qg[3]);
  const float g0 = bf2f(qg[4]), g1 = bf2f(qg[5]), g2 = bf2f(qg[6]), g3 = bf2f(qg[7]);

  float denom = 0.f;
  float4v accv = {0.f, 0.f, 0.f, 0.f};
  float4v acce = {0.f, 0.f, 0.f, 0.f};
  const int beg = offs[n], end = offs[n + 1];
  for (int i = beg + w; i < end; i += 4) {
    const int sn = srcs[i];
    const bf16x8 kv = *(const bf16x8*)(KV + (size_t)sn * 512 + lane * 8);
    const bf16x4 e4 = *(const bf16x4*)(eaC + (size_t)i * 32 + sub * 4);
    const float e0 = bf2f(e4[0]), e1 = bf2f(e4[1]), e2 = bf2f(e4[2]), e3 = bf2f(e4[3]);
    float part = q0 * bf2f(kv[0]) + q1 * bf2f(kv[1]) + q2 * bf2f(kv[2]) + q3 * bf2f(kv[3])
               + g0 * e0 + g1 * e1 + g2 * e2 + g3 * e3;
    part += __shfl_xor(part, 1);
    part += __shfl_xor(part, 2);
    part += __shfl_xor(part, 4);
    const float wgt = __expf(part * 0.17677669529663687f);  // 1/sqrt(32)
    denom += wgt;
    accv[0] += wgt * bf2f(kv[4]);
    accv[1] += wgt * bf2f(kv[5]);
    accv[2] += wgt * bf2f(kv[6]);
    accv[3] += wgt * bf2f(kv[7]);
    acce[0] += wgt * e0;
    acce[1] += wgt * e1;
    acce[2] += wgt * e2;
    acce[3] += wgt * e3;
  }
  sdn[w][lane] = denom;
#pragma unroll
  for (int j = 0; j < 4; ++j) { sav[w][lane][j] = accv[j]; sae[w][lane][j] = acce[j]; }
  __syncthreads();
  if (w == 0) {
    float D = 0.f;
    float4v av = {0.f, 0.f, 0.f, 0.f};
    float4v ae = {0.f, 0.f, 0.f, 0.f};
#pragma unroll
    for (int ww = 0; ww < 4; ++ww) {
      D += sdn[ww][lane];
#pragma unroll
      for (int j = 0; j < 4; ++j) { av[j] += sav[ww][lane][j]; ae[j] += sae[ww][lane][j]; }
    }
    const float inv = 1.0f / (D + 1e-16f);
    float4v o = *(const float4v*)(OUT + (size_t)n * 256 + c0);
#pragma unroll
    for (int j = 0; j < 4; ++j) o[j] += av[j] * inv;
    *(float4v*)(OUT + (size_t)n * 256 + c0) = o;
    bf16x4 aeb;
    aeb[0] = f2bf(ae[0] * inv); aeb[1] = f2bf(ae[1] * inv);
    aeb[2] = f2bf(ae[2] * inv); aeb[3] = f2bf(ae[3] * inv);
    *(bf16x4*)(AE + (size_t)n * 256 + c0) = aeb;
  }
}

// ---------------- post: OUT += AE@We (per-head); OUTh = bf16(OUT) ----------------
__global__ __launch_bounds__(256) void post_kernel(
    const __bf16* __restrict__ AE, const float* __restrict__ WeT,
    float* __restrict__ OUT, __bf16* __restrict__ OUTh) {
  const int lane = threadIdx.x & 63;
  const int wave = threadIdx.x >> 6;
  const int c0 = lane * 4;
  const int hg = lane >> 3;

  float4v w4[4][8];
#pragma unroll
  for (int j = 0; j < 4; ++j)
#pragma unroll
    for (int s = 0; s < 8; ++s)
      w4[j][s] = *(const float4v*)(WeT + (size_t)(c0 + j) * 32 + s * 4);

  const int nbase = blockIdx.x * 64;
  for (int it = 0; it < 16; ++it) {
    const int n = nbase + it * 4 + wave;
    if (n >= NN) return;
    const __bf16* aerow = AE + (size_t)n * HIDDEN + hg * 32;
    float aef[32];
#pragma unroll
    for (int t = 0; t < 4; ++t) {
      bf16x8 a8 = *(const bf16x8*)(aerow + t * 8);
#pragma unroll
      for (int j = 0; j < 8; ++j) aef[t * 8 + j] = bf2f(a8[j]);
    }
    float4v o = *(const float4v*)(OUT + (size_t)n * HIDDEN + c0);
#pragma unroll
    for (int j = 0; j < 4; ++j) {
      float s = 0.f;
#pragma unroll
      for (int g = 0; g < 8; ++g) {
        s += aef[g * 4 + 0] * w4[j][g][0] + aef[g * 4 + 1] * w4[j][g][1]
           + aef[g * 4 + 2] * w4[j][g][2] + aef[g * 4 + 3] * w4[j][g][3];
      }
      o[j] += s;
    }
    *(float4v*)(OUT + (size_t)n * HIDDEN + c0) = o;
    bf16x4 ob;
    ob[0] = f2bf(o[0]); ob[1] = f2bf(o[1]); ob[2] = f2bf(o[2]); ob[3] = f2bf(o[3]);
    *(bf16x4*)(OUTh + (size_t)n * HIDDEN + c0) = ob;
  }
}

extern "C" void kernel_launch(void* const* d_in, const int* in_sizes, int n_in,
                              void* d_out, int out_size, void* d_ws, size_t ws_size,
                              hipStream_t stream) {
  (void)in_sizes; (void)n_in; (void)out_size; (void)ws_size;
  const float* x   = (const float*)d_in[0];
  const int*   ei  = (const int*)d_in[1];
  const float* ea  = (const float*)d_in[2];
  const float* Wq  = (const float*)d_in[3];
  const float* bq  = (const float*)d_in[4];
  const float* Wk  = (const float*)d_in[5];
  const float* bk  = (const float*)d_in[6];
  const float* Wv  = (const float*)d_in[7];
  const float* bv  = (const float*)d_in[8];
  const float* We  = (const float*)d_in[9];
  const float* Wsk = (const float*)d_in[10];
  const float* W1  = (const float*)d_in[11];
  const float* b1  = (const float*)d_in[12];
  const float* W2  = (const float*)d_in[13];
  const float* b2  = (const float*)d_in[14];
  float* out = (float*)d_out;

  char* ws = (char*)d_ws;
  size_t off = 0;
  auto alloc = [&](size_t bytes) -> char* {
    off = (off + 255) & ~(size_t)255;
    char* p = ws + off;
    off += bytes;
    return p;
  };
  __bf16* QG   = (__bf16*)alloc((size_t)NN * 512 * 2);
  __bf16* KV   = (__bf16*)alloc((size_t)NN * 512 * 2);
  __bf16* xb   = (__bf16*)alloc((size_t)NN * 256 * 2);
  __bf16* AE   = (__bf16*)alloc((size_t)NN * 256 * 2);      // reused as H1
  __bf16* OUTh = (__bf16*)alloc((size_t)NN * 256 * 2);
  __bf16* eaC  = (__bf16*)alloc((size_t)NE * 32 * 2);
  __bf16* WTall = (__bf16*)alloc((size_t)1280 * 256 * 2);
  __bf16* WT1  = (__bf16*)alloc(256 * 256 * 2);
  __bf16* WT2  = (__bf16*)alloc(256 * 256 * 2);
  float*  ball = (float*)alloc(1280 * 4);
  float*  WeT  = (float*)alloc(256 * 32 * 4);
  int* deg    = (int*)alloc((size_t)2 * NN * 4);
  int* cursor = deg + NN;
  int* offs   = (int*)alloc((size_t)(NN + 1) * 4);
  int* srcs   = (int*)alloc((size_t)NE * 4);
  int* eids   = (int*)alloc((size_t)NE * 4);
  __bf16* H1 = AE;

  const int* srcIn = ei;       // edge_index[0]
  const int* dstIn = ei + NE;  // edge_index[1]

  // ---- fused prep (weights + x->bf16) ----
  const int prepBlocks = 1829 + (NN * 256 / 8 + 255) / 256;
  prep_kernel<<<prepBlocks, 256, 0, stream>>>(Wq, Wk, Wv, Wsk, W1, W2, We, bq, bk, bv, x,
                                              WTall, WT1, WT2, ball, WeT, xb);

  // ---- CSR build + CSR-ordered edge attrs ----
  zero_int_kernel<<<(2 * NN + 255) / 256, 256, 0, stream>>>(deg, 2 * NN);
  count_deg_kernel<<<(NE + 255) / 256, 256, 0, stream>>>(dstIn, deg, NE);
  scan_kernel<<<1, 1024, 0, stream>>>(deg, offs, NN);
  scatter_kernel<<<(NE + 255) / 256, 256, 0, stream>>>(srcIn, dstIn, offs, cursor, srcs, eids, NE);
  gather_ea_kernel<<<(NE * 4 + 255) / 256, 256, 0, stream>>>(ea, eids, eaC, NE);

  const int gy = (NN + 127) / 128;          // 235
  const int stripes = (gy + 7) / 8;         // 30
  // ---- fused node GEMM: Q|K|V|QE -> QG/KV interleaved, skip -> out (fp32) ----
  gemm_k4<10, 0, 1><<<stripes * 80, 256, 0, stream>>>(
      xb, WTall, ball, out, nullptr, QG, KV, nullptr, NN, gy);

  // ---- attention (RMW out, write AE) ----
  attn_kernel<<<NN, 256, 0, stream>>>(QG, KV, eaC, offs, srcs, out, AE);

  // ---- post: out += AE @ We (per-head), OUTh = bf16(out) ----
  post_kernel<<<(NN + 63) / 64, 256, 0, stream>>>(AE, WeT, out, OUTh);

  // ---- MLP ----
  gemm_k4<2, 2, 0><<<stripes * 16, 256, 0, stream>>>(
      OUTh, WT1, b1, nullptr, H1, nullptr, nullptr, nullptr, NN, gy);
  gemm_k4<2, 3, 0><<<stripes * 16, 256, 0, stream>>>(
      H1, WT2, b2, out, nullptr, nullptr, nullptr, out, NN, gy);
}